// Round 1
// baseline (249.235 us; speedup 1.0000x reference)
//
#include <hip/hip_runtime.h>
#include <hip/hip_bf16.h>
#include <stdint.h>

typedef short s16x8 __attribute__((ext_vector_type(8)));
typedef float f32x4 __attribute__((ext_vector_type(4)));

#define NH   32
#define NKVH 8
#define GQ   4
#define HD   128
#define QBLK 32
#define KVBLK 32

static __device__ __forceinline__ ushort f2bf(float f) {
  uint32_t u = __builtin_bit_cast(uint32_t, f);
  u += 0x7FFFu + ((u >> 16) & 1u);
  return (ushort)(u >> 16);
}

__global__ void __launch_bounds__(256)
attn_doc_causal(const float* __restrict__ qg, const float* __restrict__ kg,
                const float* __restrict__ vg, float* __restrict__ og,
                int S, int L) {
  __shared__ ushort Klds[KVBLK * 128];       // XOR-swizzled rows (byte ^= (r&7)<<4)
  __shared__ ushort Vt[HD * 40];             // [d][kv], stride 40 (16B-aligned rows)
  __shared__ ushort Plds[GQ][QBLK * 40];     // per-wave [q][kv], stride 40

  const int tid  = threadIdx.x;
  const int lane = tid & 63;
  const int wid  = tid >> 6;
  const int col  = lane & 15;
  const int hi   = lane >> 4;
  const int q0   = blockIdx.x * QBLK;
  const int kvh  = blockIdx.y;
  const int doc0 = (q0 / L) * L;
  const int q0l  = q0 - doc0;
  const int h    = kvh * GQ + wid;           // each wave = one q-head of the GQA group

  const float cs = 0.08838834764831845f * 1.4426950408889634f;  // SCALE*log2(e)

  // ---- Q fragments (fp32 global -> bf16 regs), A-frag: row=lane&15, k=hi*8+j ----
  s16x8 qf[2][4];
#pragma unroll
  for (int st = 0; st < 2; ++st) {
    const float* qrow = qg + (size_t)(q0 + st * 16 + col) * (NH * HD) + h * HD + hi * 8;
#pragma unroll
    for (int dc = 0; dc < 4; ++dc) {
      float4 x = ((const float4*)(qrow + dc * 32))[0];
      float4 y = ((const float4*)(qrow + dc * 32))[1];
      s16x8 f;
      f[0] = (short)f2bf(x.x); f[1] = (short)f2bf(x.y);
      f[2] = (short)f2bf(x.z); f[3] = (short)f2bf(x.w);
      f[4] = (short)f2bf(y.x); f[5] = (short)f2bf(y.y);
      f[6] = (short)f2bf(y.z); f[7] = (short)f2bf(y.w);
      qf[st][dc] = f;
    }
  }

  f32x4 o[2][8];
  float m[2][4], ls[2][4];
#pragma unroll
  for (int st = 0; st < 2; ++st) {
#pragma unroll
    for (int dt = 0; dt < 8; ++dt) { f32x4 z = {0.f, 0.f, 0.f, 0.f}; o[st][dt] = z; }
#pragma unroll
    for (int r = 0; r < 4; ++r) { m[st][r] = -__builtin_inff(); ls[st][r] = 0.f; }
  }

  const int ntiles = q0l / KVBLK + 1;
  const int srow = tid >> 3;            // staging: row 0..31
  const int scol = (tid & 7) << 4;      // staging: col0 0..112 (16 floats each)

  for (int t = 0; t < ntiles; ++t) {
    const int kv0 = doc0 + t * KVBLK;
    // ---- issue global loads early (regs), then barrier, then LDS writes ----
    const float* ks = kg + (size_t)(kv0 + srow) * (NKVH * HD) + kvh * HD + scol;
    const float* vs = vg + (size_t)(kv0 + srow) * (NKVH * HD) + kvh * HD + scol;
    float4 k0 = ((const float4*)ks)[0], k1 = ((const float4*)ks)[1],
           k2 = ((const float4*)ks)[2], k3 = ((const float4*)ks)[3];
    float4 v0 = ((const float4*)vs)[0], v1 = ((const float4*)vs)[1],
           v2 = ((const float4*)vs)[2], v3 = ((const float4*)vs)[3];

    __syncthreads();   // previous tile fully consumed by all waves

    {
      const int sw = (srow & 7) << 3;   // ushort-index XOR = byte>>1 of (r&7)<<4
      s16x8 lo, hb;
      lo[0]=(short)f2bf(k0.x); lo[1]=(short)f2bf(k0.y); lo[2]=(short)f2bf(k0.z); lo[3]=(short)f2bf(k0.w);
      lo[4]=(short)f2bf(k1.x); lo[5]=(short)f2bf(k1.y); lo[6]=(short)f2bf(k1.z); lo[7]=(short)f2bf(k1.w);
      hb[0]=(short)f2bf(k2.x); hb[1]=(short)f2bf(k2.y); hb[2]=(short)f2bf(k2.z); hb[3]=(short)f2bf(k2.w);
      hb[4]=(short)f2bf(k3.x); hb[5]=(short)f2bf(k3.y); hb[6]=(short)f2bf(k3.z); hb[7]=(short)f2bf(k3.w);
      *(s16x8*)&Klds[srow * 128 + (scol ^ sw)]       = lo;
      *(s16x8*)&Klds[srow * 128 + ((scol + 8) ^ sw)] = hb;
      float vv[16] = {v0.x,v0.y,v0.z,v0.w, v1.x,v1.y,v1.z,v1.w,
                      v2.x,v2.y,v2.z,v2.w, v3.x,v3.y,v3.z,v3.w};
#pragma unroll
      for (int j = 0; j < 16; ++j)
        Vt[(scol + j) * 40 + srow] = f2bf(vv[j]);   // transpose-on-store
    }
    __syncthreads();

    // ---- QK^T: S[32q x 32k] ----
    s16x8 kf[2][4];
#pragma unroll
    for (int kt = 0; kt < 2; ++kt) {
      const int r = kt * 16 + col;
      const int sw = (r & 7) << 3;
#pragma unroll
      for (int dc = 0; dc < 4; ++dc)
        kf[kt][dc] = *(const s16x8*)&Klds[r * 128 + ((dc * 32 + hi * 8) ^ sw)];
    }
    f32x4 s[2][2];
#pragma unroll
    for (int st = 0; st < 2; ++st)
#pragma unroll
      for (int kt = 0; kt < 2; ++kt) {
        f32x4 acc = {0.f, 0.f, 0.f, 0.f};
#pragma unroll
        for (int dc = 0; dc < 4; ++dc)
          acc = __builtin_amdgcn_mfma_f32_16x16x32_bf16(qf[st][dc], kf[kt][dc], acc, 0, 0, 0);
        s[st][kt] = acc;
      }

    if (t == ntiles - 1) {   // diagonal tile: causal mask (kv0l == q0l here)
#pragma unroll
      for (int st = 0; st < 2; ++st)
#pragma unroll
        for (int kt = 0; kt < 2; ++kt)
#pragma unroll
          for (int r = 0; r < 4; ++r) {
            int qr = st * 16 + hi * 4 + r;
            int kc = kt * 16 + col;
            if (kc > qr) s[st][kt][r] = -__builtin_inff();
          }
    }

    // ---- online softmax (rows live on 16-lane groups) ----
#pragma unroll
    for (int st = 0; st < 2; ++st) {
      float pm[4], ps[4], corr[4];
#pragma unroll
      for (int r = 0; r < 4; ++r) pm[r] = fmaxf(s[st][0][r], s[st][1][r]);
#pragma unroll
      for (int off = 1; off < 16; off <<= 1)
#pragma unroll
        for (int r = 0; r < 4; ++r) pm[r] = fmaxf(pm[r], __shfl_xor(pm[r], off));
#pragma unroll
      for (int r = 0; r < 4; ++r) {
        float mn = fmaxf(m[st][r], pm[r]);
        corr[r] = __builtin_amdgcn_exp2f((m[st][r] - mn) * cs);
        m[st][r] = mn;
        float p0 = __builtin_amdgcn_exp2f((s[st][0][r] - mn) * cs);
        float p1 = __builtin_amdgcn_exp2f((s[st][1][r] - mn) * cs);
        s[st][0][r] = p0; s[st][1][r] = p1;
        ps[r] = p0 + p1;
      }
#pragma unroll
      for (int off = 1; off < 16; off <<= 1)
#pragma unroll
        for (int r = 0; r < 4; ++r) ps[r] += __shfl_xor(ps[r], off);
#pragma unroll
      for (int r = 0; r < 4; ++r) ls[st][r] = ls[st][r] * corr[r] + ps[r];
#pragma unroll
      for (int dt = 0; dt < 8; ++dt)
#pragma unroll
        for (int r = 0; r < 4; ++r) o[st][dt][r] *= corr[r];
      // P -> bf16 -> per-wave LDS
#pragma unroll
      for (int r = 0; r < 4; ++r) {
        ushort* dst = &Plds[wid][(st * 16 + hi * 4 + r) * 40];
        dst[col]      = f2bf(s[st][0][r]);
        dst[16 + col] = f2bf(s[st][1][r]);
      }
    }

    asm volatile("s_waitcnt lgkmcnt(0)" ::: "memory");  // P writes visible wave-wide
    __builtin_amdgcn_sched_barrier(0);                  // rule #18: pin reads after wait

    // ---- PV: O[32q x 128d] += P[32q x 32k] * V[32k x 128d] ----
    s16x8 af[2];
#pragma unroll
    for (int st = 0; st < 2; ++st)
      af[st] = *(const s16x8*)&Plds[wid][(st * 16 + col) * 40 + hi * 8];
#pragma unroll
    for (int dt = 0; dt < 8; ++dt) {
      s16x8 vf = *(const s16x8*)&Vt[(dt * 16 + col) * 40 + hi * 8];
#pragma unroll
      for (int st = 0; st < 2; ++st)
        o[st][dt] = __builtin_amdgcn_mfma_f32_16x16x32_bf16(af[st], vf, o[st][dt], 0, 0, 0);
    }
  }

  // ---- epilogue: O / l, fp32 store ----
#pragma unroll
  for (int st = 0; st < 2; ++st) {
    float rl[4];
#pragma unroll
    for (int r = 0; r < 4; ++r) rl[r] = 1.f / ls[st][r];
#pragma unroll
    for (int dt = 0; dt < 8; ++dt)
#pragma unroll
      for (int r = 0; r < 4; ++r) {
        int row = q0 + st * 16 + hi * 4 + r;
        og[((size_t)h * S + row) * HD + dt * 16 + col] = o[st][dt][r] * rl[r];
      }
  }
}

extern "C" void kernel_launch(void* const* d_in, const int* in_sizes, int n_in,
                              void* d_out, int out_size, void* d_ws, size_t ws_size,
                              hipStream_t stream) {
  const float* q = (const float*)d_in[0];
  const float* k = (const float*)d_in[1];
  const float* v = (const float*)d_in[2];
  float* out = (float*)d_out;
  const int S  = in_sizes[1] / (NKVH * HD);   // 4096
  const int nd = in_sizes[3] - 1;             // 4 docs
  const int L  = S / nd;                      // 1024 (equal-length packing per reference)
  dim3 grid(S / QBLK, NKVH);
  attn_doc_causal<<<grid, 256, 0, stream>>>(q, k, v, out, S, L);
}

// Round 2
// 161.393 us; speedup vs baseline: 1.5443x; 1.5443x over previous
//
#include <hip/hip_runtime.h>
#include <hip/hip_bf16.h>
#include <stdint.h>

typedef short s16x8 __attribute__((ext_vector_type(8)));
typedef float f32x4 __attribute__((ext_vector_type(4)));

#define NH    32
#define NKVH  8
#define GQ    4
#define HD    128
#define QBLK  64
#define KVBLK 64

static __device__ __forceinline__ ushort f2bf(float f) {
  uint32_t u = __builtin_bit_cast(uint32_t, f);
  u += 0x7FFFu + ((u >> 16) & 1u);
  return (ushort)(u >> 16);
}

// chunk-XOR swizzles (bits 3-5 of the u16 element index within a row)
static __device__ __forceinline__ int swzV(int d) {
  return (((d & 7) ^ ((d >> 4) & 7)) << 3);
}

__global__ void __launch_bounds__(512, 2)
attn_doc_causal(const float* __restrict__ qg, const float* __restrict__ kg,
                const float* __restrict__ vg, float* __restrict__ og,
                int S, int L) {
  __shared__ ushort Klds[KVBLK * HD];      // [kv][d], e^((kv&7)<<3)
  __shared__ ushort Vt[HD * KVBLK];        // [d][kv], e^swzV(d)
  __shared__ ushort Plds[8][32 * KVBLK];   // per-wave [q][kv], e^(((q>>1)&7)<<3)

  const int tid  = threadIdx.x;
  const int lane = tid & 63;
  const int wid  = tid >> 6;
  const int col  = lane & 15;
  const int hi   = lane >> 4;
  const int hq   = wid & 3;          // head within GQA group
  const int qh   = wid >> 2;         // which 32-row q half
  const int bid  = blockIdx.x;
  const int kvh  = bid & 7;          // head-aligned XCD mapping (round-robin dispatch)
  const int q0   = (bid >> 3) * QBLK;
  const int doc0 = (q0 / L) * L;
  const int q0l  = q0 - doc0;
  const int h    = kvh * GQ + hq;
  const int qw   = q0 + qh * 32;

  const float cs = 0.08838834764831845f * 1.4426950408889634f;  // SCALE*log2(e)

  // ---- Q fragments: A-frag row=lane&15, k=hi*8+j (+32*dc) ----
  s16x8 qf[2][4];
#pragma unroll
  for (int st = 0; st < 2; ++st) {
    const float* qrow = qg + (size_t)(qw + st * 16 + col) * (NH * HD) + h * HD + hi * 8;
#pragma unroll
    for (int dc = 0; dc < 4; ++dc) {
      float4 x = ((const float4*)(qrow + dc * 32))[0];
      float4 y = ((const float4*)(qrow + dc * 32))[1];
      s16x8 f;
      f[0] = (short)f2bf(x.x); f[1] = (short)f2bf(x.y);
      f[2] = (short)f2bf(x.z); f[3] = (short)f2bf(x.w);
      f[4] = (short)f2bf(y.x); f[5] = (short)f2bf(y.y);
      f[6] = (short)f2bf(y.z); f[7] = (short)f2bf(y.w);
      qf[st][dc] = f;
    }
  }

  f32x4 o[2][8];
  float m[2][4], ls[2][4];
#pragma unroll
  for (int st = 0; st < 2; ++st) {
#pragma unroll
    for (int dt = 0; dt < 8; ++dt) { f32x4 z = {0.f, 0.f, 0.f, 0.f}; o[st][dt] = z; }
#pragma unroll
    for (int r = 0; r < 4; ++r) { m[st][r] = -__builtin_inff(); ls[st][r] = 0.f; }
  }

  const int ntiles = q0l / KVBLK + 1;
  const int srow = tid >> 3;            // 0..63
  const int scol = (tid & 7) << 4;      // 0..112, 16 floats per thread-row

  const size_t kvstr = (size_t)(NKVH * HD);
  const float* kbase = kg + (size_t)kvh * HD + scol;
  const float* vbase = vg + (size_t)kvh * HD + scol;

  // prologue: load tile 0
  float4 k0, k1, k2, k3, v0, v1, v2, v3;
  {
    const float* ks = kbase + (size_t)(doc0 + srow) * kvstr;
    const float* vs = vbase + (size_t)(doc0 + srow) * kvstr;
    k0 = ((const float4*)ks)[0]; k1 = ((const float4*)ks)[1];
    k2 = ((const float4*)ks)[2]; k3 = ((const float4*)ks)[3];
    v0 = ((const float4*)vs)[0]; v1 = ((const float4*)vs)[1];
    v2 = ((const float4*)vs)[2]; v3 = ((const float4*)vs)[3];
  }

  for (int t = 0; t < ntiles; ++t) {
    __syncthreads();   // previous tile's LDS fully consumed
    // ---- stage K (swizzled row-major) + V (swizzled transpose) ----
    {
      const int swK = (srow & 7) << 3;
      s16x8 lo, hb;
      lo[0]=(short)f2bf(k0.x); lo[1]=(short)f2bf(k0.y); lo[2]=(short)f2bf(k0.z); lo[3]=(short)f2bf(k0.w);
      lo[4]=(short)f2bf(k1.x); lo[5]=(short)f2bf(k1.y); lo[6]=(short)f2bf(k1.z); lo[7]=(short)f2bf(k1.w);
      hb[0]=(short)f2bf(k2.x); hb[1]=(short)f2bf(k2.y); hb[2]=(short)f2bf(k2.z); hb[3]=(short)f2bf(k2.w);
      hb[4]=(short)f2bf(k3.x); hb[5]=(short)f2bf(k3.y); hb[6]=(short)f2bf(k3.z); hb[7]=(short)f2bf(k3.w);
      *(s16x8*)&Klds[srow * HD + (scol ^ swK)]       = lo;
      *(s16x8*)&Klds[srow * HD + ((scol + 8) ^ swK)] = hb;
      float vv[16] = {v0.x,v0.y,v0.z,v0.w, v1.x,v1.y,v1.z,v1.w,
                      v2.x,v2.y,v2.z,v2.w, v3.x,v3.y,v3.z,v3.w};
#pragma unroll
      for (int j = 0; j < 16; ++j) {
        int d = scol + j;
        Vt[d * KVBLK + (srow ^ swzV(d))] = f2bf(vv[j]);
      }
    }
    __syncthreads();

    // ---- prefetch next tile (latency hides under QK+softmax+PV) ----
    if (t + 1 < ntiles) {
      const float* ks = kbase + (size_t)(doc0 + (t + 1) * KVBLK + srow) * kvstr;
      const float* vs = vbase + (size_t)(doc0 + (t + 1) * KVBLK + srow) * kvstr;
      k0 = ((const float4*)ks)[0]; k1 = ((const float4*)ks)[1];
      k2 = ((const float4*)ks)[2]; k3 = ((const float4*)ks)[3];
      v0 = ((const float4*)vs)[0]; v1 = ((const float4*)vs)[1];
      v2 = ((const float4*)vs)[2]; v3 = ((const float4*)vs)[3];
    }

    // ---- QK^T: S[32q x 64k] per wave ----
    f32x4 sA[2][4];
#pragma unroll
    for (int kt = 0; kt < 4; ++kt) {
      const int r = kt * 16 + col;
      const int swr = (r & 7) << 3;
      s16x8 kf[4];
#pragma unroll
      for (int dc = 0; dc < 4; ++dc)
        kf[dc] = *(const s16x8*)&Klds[r * HD + ((dc * 32 + hi * 8) ^ swr)];
      __builtin_amdgcn_s_setprio(1);
#pragma unroll
      for (int st = 0; st < 2; ++st) {
        f32x4 acc = {0.f, 0.f, 0.f, 0.f};
#pragma unroll
        for (int dc = 0; dc < 4; ++dc)
          acc = __builtin_amdgcn_mfma_f32_16x16x32_bf16(qf[st][dc], kf[dc], acc, 0, 0, 0);
        sA[st][kt] = acc;
      }
      __builtin_amdgcn_s_setprio(0);
    }

    if (t == ntiles - 1) {   // diagonal tile: causal mask
#pragma unroll
      for (int st = 0; st < 2; ++st)
#pragma unroll
        for (int kt = 0; kt < 4; ++kt)
#pragma unroll
          for (int r = 0; r < 4; ++r) {
            int qr = qh * 32 + st * 16 + hi * 4 + r;
            int kc = kt * 16 + col;
            if (kc > qr) sA[st][kt][r] = -__builtin_inff();
          }
    }

    // ---- online softmax (rows on 16-lane groups) + P store ----
#pragma unroll
    for (int st = 0; st < 2; ++st) {
      float pm[4], ps[4], corr[4];
#pragma unroll
      for (int r = 0; r < 4; ++r)
        pm[r] = fmaxf(fmaxf(sA[st][0][r], sA[st][1][r]), fmaxf(sA[st][2][r], sA[st][3][r]));
#pragma unroll
      for (int off = 1; off < 16; off <<= 1)
#pragma unroll
        for (int r = 0; r < 4; ++r) pm[r] = fmaxf(pm[r], __shfl_xor(pm[r], off));
#pragma unroll
      for (int r = 0; r < 4; ++r) {
        float mn = fmaxf(m[st][r], pm[r]);
        corr[r] = __builtin_amdgcn_exp2f((m[st][r] - mn) * cs);
        m[st][r] = mn;
        float sum = 0.f;
#pragma unroll
        for (int kt = 0; kt < 4; ++kt) {
          float p = __builtin_amdgcn_exp2f((sA[st][kt][r] - mn) * cs);
          sA[st][kt][r] = p;
          sum += p;
        }
        ps[r] = sum;
      }
#pragma unroll
      for (int off = 1; off < 16; off <<= 1)
#pragma unroll
        for (int r = 0; r < 4; ++r) ps[r] += __shfl_xor(ps[r], off);
#pragma unroll
      for (int r = 0; r < 4; ++r) ls[st][r] = ls[st][r] * corr[r] + ps[r];
#pragma unroll
      for (int dt = 0; dt < 8; ++dt)
#pragma unroll
        for (int r = 0; r < 4; ++r) o[st][dt][r] *= corr[r];
#pragma unroll
      for (int r = 0; r < 4; ++r) {
        int q = st * 16 + hi * 4 + r;
        int xq = ((q >> 1) & 7) << 3;
        ushort* dst = &Plds[wid][q * KVBLK];
        dst[(col)      ^ xq] = f2bf(sA[st][0][r]);
        dst[(16 + col) ^ xq] = f2bf(sA[st][1][r]);
        dst[(32 + col) ^ xq] = f2bf(sA[st][2][r]);
        dst[(48 + col) ^ xq] = f2bf(sA[st][3][r]);
      }
    }

    asm volatile("s_waitcnt lgkmcnt(0)" ::: "memory");  // wave-local P visibility
    __builtin_amdgcn_sched_barrier(0);                  // rule #18

    // ---- PV: O[32q x 128d] += P[32q x 64k] * V[64k x 128d] ----
    s16x8 af[2][2];
#pragma unroll
    for (int st = 0; st < 2; ++st) {
      int q2 = st * 16 + col;
      int xq = ((q2 >> 1) & 7) << 3;
#pragma unroll
      for (int ksb = 0; ksb < 2; ++ksb)
        af[st][ksb] = *(const s16x8*)&Plds[wid][q2 * KVBLK + ((ksb * 32 + hi * 8) ^ xq)];
    }
#pragma unroll
    for (int dt = 0; dt < 8; ++dt) {
      int d2 = dt * 16 + col;
      int xv = swzV(d2);
#pragma unroll
      for (int ksb = 0; ksb < 2; ++ksb) {
        s16x8 vf = *(const s16x8*)&Vt[d2 * KVBLK + ((ksb * 32 + hi * 8) ^ xv)];
        __builtin_amdgcn_s_setprio(1);
#pragma unroll
        for (int st = 0; st < 2; ++st)
          o[st][dt] = __builtin_amdgcn_mfma_f32_16x16x32_bf16(af[st][ksb], vf, o[st][dt], 0, 0, 0);
        __builtin_amdgcn_s_setprio(0);
      }
    }
  }

  // ---- epilogue ----
#pragma unroll
  for (int st = 0; st < 2; ++st) {
    float rl[4];
#pragma unroll
    for (int r = 0; r < 4; ++r) rl[r] = 1.f / ls[st][r];
#pragma unroll
    for (int dt = 0; dt < 8; ++dt)
#pragma unroll
      for (int r = 0; r < 4; ++r) {
        int row = qw + st * 16 + hi * 4 + r;
        og[((size_t)h * S + row) * HD + dt * 16 + col] = o[st][dt][r] * rl[r];
      }
  }
}

extern "C" void kernel_launch(void* const* d_in, const int* in_sizes, int n_in,
                              void* d_out, int out_size, void* d_ws, size_t ws_size,
                              hipStream_t stream) {
  const float* q = (const float*)d_in[0];
  const float* k = (const float*)d_in[1];
  const float* v = (const float*)d_in[2];
  float* out = (float*)d_out;
  const int S  = in_sizes[1] / (NKVH * HD);   // 4096
  const int nd = in_sizes[3] - 1;             // 4 docs
  const int L  = S / nd;                      // 1024
  const int nblk = (S / QBLK) * NKVH;         // 512
  attn_doc_causal<<<nblk, 512, 0, stream>>>(q, k, v, out, S, L);
}

// Round 3
// 116.159 us; speedup vs baseline: 2.1456x; 1.3894x over previous
//
#include <hip/hip_runtime.h>
#include <hip/hip_bf16.h>
#include <stdint.h>

typedef short s16x8 __attribute__((ext_vector_type(8)));
typedef float f32x4 __attribute__((ext_vector_type(4)));

#define NH    32
#define NKVH  8
#define GQ    4
#define HD    128
#define QBLK  64
#define KVBLK 64

static __device__ __forceinline__ ushort f2bf(float f) {
  // compiler fuses pairs into v_cvt_pk_bf16_f32 (m240)
  return __bfloat16_as_ushort(__float2bfloat16(f));
}

static __device__ __forceinline__ int swzV(int d) {
  return (((d & 7) ^ ((d >> 4) & 7)) << 3);
}

__global__ void __launch_bounds__(512, 2)
attn_doc_causal(const float* __restrict__ qg, const float* __restrict__ kg,
                const float* __restrict__ vg, float* __restrict__ og,
                int S, int L) {
  __shared__ ushort Klds[KVBLK * HD];      // [kv][d], ^((kv&7)<<3)
  __shared__ ushort Vt[HD * KVBLK];        // [d][kv], ^swzV(d)
  __shared__ ushort Plds[8][32 * KVBLK];   // per-wave [q][kv], ^(((q>>1)&7)<<3)

  const int tid  = threadIdx.x;
  const int lane = tid & 63;
  const int wid  = tid >> 6;
  const int col  = lane & 15;
  const int hi   = lane >> 4;
  const int hq   = wid & 3;
  const int qh   = wid >> 2;
  const int bid  = blockIdx.x;
  const int kvh  = bid & 7;                 // head-aligned XCD mapping
  const int nq   = L / QBLK;                // q-tiles per doc (16)
  const int npair= nq >> 1;                 // 8
  const int pidx = bid >> 3;                // 0..(nd*npair-1)
  const int doc  = pidx / npair;
  const int ipr  = pidx % npair;
  const int doc0 = doc * L;
  const int h    = kvh * GQ + hq;

  const float cs  = 0.08838834764831845f * 1.4426950408889634f;  // SCALE*log2(e)
  const float THR = 62.0f;                                       // raw-score defer-max threshold

  const int srow = tid >> 3;
  const int scol = (tid & 7) << 4;
  const size_t kvstr = (size_t)(NKVH * HD);
  const float* kbase = kg + (size_t)kvh * HD + scol;
  const float* vbase = vg + (size_t)kvh * HD + scol;

  // two q-tiles per block: (nq-1-ipr) then (ipr) -> 17 kv-tile-updates for every block
  for (int ph = 0; ph < 2; ++ph) {
    const int qt = ph ? ipr : (nq - 1 - ipr);
    const int q0 = doc0 + qt * QBLK;
    const int qw = q0 + qh * 32;
    const int ntiles = qt + 1;

    // ---- Q fragments ----
    s16x8 qf[2][4];
#pragma unroll
    for (int st = 0; st < 2; ++st) {
      const float* qrow = qg + (size_t)(qw + st * 16 + col) * (NH * HD) + h * HD + hi * 8;
#pragma unroll
      for (int dc = 0; dc < 4; ++dc) {
        float4 x = ((const float4*)(qrow + dc * 32))[0];
        float4 y = ((const float4*)(qrow + dc * 32))[1];
        s16x8 f;
        f[0] = (short)f2bf(x.x); f[1] = (short)f2bf(x.y);
        f[2] = (short)f2bf(x.z); f[3] = (short)f2bf(x.w);
        f[4] = (short)f2bf(y.x); f[5] = (short)f2bf(y.y);
        f[6] = (short)f2bf(y.z); f[7] = (short)f2bf(y.w);
        qf[st][dc] = f;
      }
    }

    f32x4 o[2][8];
    float m[2][4], ls[2][4];
#pragma unroll
    for (int st = 0; st < 2; ++st) {
#pragma unroll
      for (int dt = 0; dt < 8; ++dt) { f32x4 z = {0.f, 0.f, 0.f, 0.f}; o[st][dt] = z; }
#pragma unroll
      for (int r = 0; r < 4; ++r) { m[st][r] = -__builtin_inff(); ls[st][r] = 0.f; }
    }

    // prologue load tile 0
    float4 k0, k1, k2, k3, v0, v1, v2, v3;
    {
      const float* ks = kbase + (size_t)(doc0 + srow) * kvstr;
      const float* vs = vbase + (size_t)(doc0 + srow) * kvstr;
      k0 = ((const float4*)ks)[0]; k1 = ((const float4*)ks)[1];
      k2 = ((const float4*)ks)[2]; k3 = ((const float4*)ks)[3];
      v0 = ((const float4*)vs)[0]; v1 = ((const float4*)vs)[1];
      v2 = ((const float4*)vs)[2]; v3 = ((const float4*)vs)[3];
    }

    for (int t = 0; t < ntiles; ++t) {
      __syncthreads();
      // ---- stage K (swizzled) + V (swizzled transpose) ----
      {
        const int swK = (srow & 7) << 3;
        s16x8 lo, hb;
        lo[0]=(short)f2bf(k0.x); lo[1]=(short)f2bf(k0.y); lo[2]=(short)f2bf(k0.z); lo[3]=(short)f2bf(k0.w);
        lo[4]=(short)f2bf(k1.x); lo[5]=(short)f2bf(k1.y); lo[6]=(short)f2bf(k1.z); lo[7]=(short)f2bf(k1.w);
        hb[0]=(short)f2bf(k2.x); hb[1]=(short)f2bf(k2.y); hb[2]=(short)f2bf(k2.z); hb[3]=(short)f2bf(k2.w);
        hb[4]=(short)f2bf(k3.x); hb[5]=(short)f2bf(k3.y); hb[6]=(short)f2bf(k3.z); hb[7]=(short)f2bf(k3.w);
        *(s16x8*)&Klds[srow * HD + (scol ^ swK)]       = lo;
        *(s16x8*)&Klds[srow * HD + ((scol + 8) ^ swK)] = hb;
        float vv[16] = {v0.x,v0.y,v0.z,v0.w, v1.x,v1.y,v1.z,v1.w,
                        v2.x,v2.y,v2.z,v2.w, v3.x,v3.y,v3.z,v3.w};
#pragma unroll
        for (int j = 0; j < 16; ++j) {
          int d = scol + j;
          Vt[d * KVBLK + (srow ^ swzV(d))] = f2bf(vv[j]);
        }
      }
      __syncthreads();

      // ---- prefetch next tile ----
      if (t + 1 < ntiles) {
        const float* ks = kbase + (size_t)(doc0 + (t + 1) * KVBLK + srow) * kvstr;
        const float* vs = vbase + (size_t)(doc0 + (t + 1) * KVBLK + srow) * kvstr;
        k0 = ((const float4*)ks)[0]; k1 = ((const float4*)ks)[1];
        k2 = ((const float4*)ks)[2]; k3 = ((const float4*)ks)[3];
        v0 = ((const float4*)vs)[0]; v1 = ((const float4*)vs)[1];
        v2 = ((const float4*)vs)[2]; v3 = ((const float4*)vs)[3];
      } else if (ph == 0) {
        // prefetch phase-1's tile 0 (kv strip restarts at doc0)
        const float* ks = kbase + (size_t)(doc0 + srow) * kvstr;
        const float* vs = vbase + (size_t)(doc0 + srow) * kvstr;
        k0 = ((const float4*)ks)[0]; k1 = ((const float4*)ks)[1];
        k2 = ((const float4*)ks)[2]; k3 = ((const float4*)ks)[3];
        v0 = ((const float4*)vs)[0]; v1 = ((const float4*)vs)[1];
        v2 = ((const float4*)vs)[2]; v3 = ((const float4*)vs)[3];
      }

      // ---- QK^T ----
      f32x4 sA[2][4];
#pragma unroll
      for (int kt = 0; kt < 4; ++kt) {
        const int r = kt * 16 + col;
        const int swr = (r & 7) << 3;
        s16x8 kf[4];
#pragma unroll
        for (int dc = 0; dc < 4; ++dc)
          kf[dc] = *(const s16x8*)&Klds[r * HD + ((dc * 32 + hi * 8) ^ swr)];
        __builtin_amdgcn_s_setprio(1);
#pragma unroll
        for (int st = 0; st < 2; ++st) {
          f32x4 acc = {0.f, 0.f, 0.f, 0.f};
#pragma unroll
          for (int dc = 0; dc < 4; ++dc)
            acc = __builtin_amdgcn_mfma_f32_16x16x32_bf16(qf[st][dc], kf[dc], acc, 0, 0, 0);
          sA[st][kt] = acc;
        }
        __builtin_amdgcn_s_setprio(0);
      }

      if (t == ntiles - 1) {   // diagonal tile
#pragma unroll
        for (int st = 0; st < 2; ++st)
#pragma unroll
          for (int kt = 0; kt < 4; ++kt)
#pragma unroll
            for (int r = 0; r < 4; ++r) {
              int qr = qh * 32 + st * 16 + hi * 4 + r;
              int kc = kt * 16 + col;
              if (kc > qr) sA[st][kt][r] = -__builtin_inff();
            }
      }

      // ---- online softmax with defer-max (T13) ----
#pragma unroll
      for (int st = 0; st < 2; ++st) {
        float pm[4], ps[4];
#pragma unroll
        for (int r = 0; r < 4; ++r)
          pm[r] = fmaxf(fmaxf(sA[st][0][r], sA[st][1][r]), fmaxf(sA[st][2][r], sA[st][3][r]));
#pragma unroll
        for (int off = 1; off < 16; off <<= 1)
#pragma unroll
          for (int r = 0; r < 4; ++r) pm[r] = fmaxf(pm[r], __shfl_xor(pm[r], off));

        int need = 0;
#pragma unroll
        for (int r = 0; r < 4; ++r) need |= (pm[r] > m[st][r] + THR) ? 1 : 0;
        if (__any(need)) {
#pragma unroll
          for (int r = 0; r < 4; ++r) {
            float mn = fmaxf(m[st][r], pm[r]);
            float corr = __builtin_amdgcn_exp2f((m[st][r] - mn) * cs);
            m[st][r] = mn;
            ls[st][r] *= corr;
#pragma unroll
            for (int dt = 0; dt < 8; ++dt) o[st][dt][r] *= corr;
          }
        }
#pragma unroll
        for (int r = 0; r < 4; ++r) {
          float sum = 0.f;
#pragma unroll
          for (int kt = 0; kt < 4; ++kt) {
            float p = __builtin_amdgcn_exp2f((sA[st][kt][r] - m[st][r]) * cs);
            sA[st][kt][r] = p;
            sum += p;
          }
          ps[r] = sum;
        }
#pragma unroll
        for (int off = 1; off < 16; off <<= 1)
#pragma unroll
          for (int r = 0; r < 4; ++r) ps[r] += __shfl_xor(ps[r], off);
#pragma unroll
        for (int r = 0; r < 4; ++r) ls[st][r] += ps[r];
#pragma unroll
        for (int r = 0; r < 4; ++r) {
          int q = st * 16 + hi * 4 + r;
          int xq = ((q >> 1) & 7) << 3;
          ushort* dst = &Plds[wid][q * KVBLK];
          dst[(col)      ^ xq] = f2bf(sA[st][0][r]);
          dst[(16 + col) ^ xq] = f2bf(sA[st][1][r]);
          dst[(32 + col) ^ xq] = f2bf(sA[st][2][r]);
          dst[(48 + col) ^ xq] = f2bf(sA[st][3][r]);
        }
      }

      asm volatile("s_waitcnt lgkmcnt(0)" ::: "memory");
      __builtin_amdgcn_sched_barrier(0);   // rule #18

      // ---- PV ----
      s16x8 af[2][2];
#pragma unroll
      for (int st = 0; st < 2; ++st) {
        int q2 = st * 16 + col;
        int xq = ((q2 >> 1) & 7) << 3;
#pragma unroll
        for (int ksb = 0; ksb < 2; ++ksb)
          af[st][ksb] = *(const s16x8*)&Plds[wid][q2 * KVBLK + ((ksb * 32 + hi * 8) ^ xq)];
      }
#pragma unroll
      for (int dt = 0; dt < 8; ++dt) {
        int d2 = dt * 16 + col;
        int xv = swzV(d2);
#pragma unroll
        for (int ksb = 0; ksb < 2; ++ksb) {
          s16x8 vf = *(const s16x8*)&Vt[d2 * KVBLK + ((ksb * 32 + hi * 8) ^ xv)];
          __builtin_amdgcn_s_setprio(1);
#pragma unroll
          for (int st = 0; st < 2; ++st)
            o[st][dt] = __builtin_amdgcn_mfma_f32_16x16x32_bf16(af[st][ksb], vf, o[st][dt], 0, 0, 0);
          __builtin_amdgcn_s_setprio(0);
        }
      }
    }

    // ---- epilogue ----
#pragma unroll
    for (int st = 0; st < 2; ++st) {
      float rl[4];
#pragma unroll
      for (int r = 0; r < 4; ++r) rl[r] = 1.f / ls[st][r];
#pragma unroll
      for (int dt = 0; dt < 8; ++dt)
#pragma unroll
        for (int r = 0; r < 4; ++r) {
          int row = qw + st * 16 + hi * 4 + r;
          og[((size_t)h * S + row) * HD + dt * 16 + col] = o[st][dt][r] * rl[r];
        }
    }
  }
}

extern "C" void kernel_launch(void* const* d_in, const int* in_sizes, int n_in,
                              void* d_out, int out_size, void* d_ws, size_t ws_size,
                              hipStream_t stream) {
  const float* q = (const float*)d_in[0];
  const float* k = (const float*)d_in[1];
  const float* v = (const float*)d_in[2];
  float* out = (float*)d_out;
  const int S  = in_sizes[1] / (NKVH * HD);   // 4096
  const int nd = in_sizes[3] - 1;             // 4 docs
  const int L  = S / nd;                      // 1024
  const int nblk = (S / (2 * QBLK)) * NKVH;   // 256: balanced q-tile pairs
  attn_doc_causal<<<nblk, 512, 0, stream>>>(q, k, v, out, S, L);
}